// Round 3
// baseline (1604.093 us; speedup 1.0000x reference)
//
#include <hip/hip_runtime.h>

#define D_  128
#define DH_ 32

typedef __attribute__((ext_vector_type(8))) short bf16x8;  // MFMA A/B frag (4 VGPRs)
typedef __attribute__((ext_vector_type(4))) float f32x4;   // MFMA C/D frag

// Pack two fp32 -> two bf16 (truncation) in ONE v_perm_b32.
// dst = (hi16(hi) << 16) | hi16(lo); sel bytes: {7,6,3,2} over {a:b}
__device__ __forceinline__ unsigned pk_bf16(float lo, float hi) {
    return __builtin_amdgcn_perm(__float_as_uint(hi), __float_as_uint(lo), 0x07060302u);
}

// Build start[p] = first row index of segment p (pids sorted); start[P] = N.
__global__ __launch_bounds__(256) void seg_offsets(
    const int* __restrict__ pid, int* __restrict__ start, int N, int P)
{
    int i = blockIdx.x * 256 + threadIdx.x;
    if (i >= N) return;
    int p1 = pid[i];
    int p0 = (i == 0) ? -1 : pid[i - 1];
    for (int p = p0 + 1; p <= p1; ++p) start[p] = i;   // covers (p0, p1]
    if (i == N - 1)
        for (int p = p1 + 1; p <= P; ++p) start[p] = N;
}

// One wave = one segment. MFMA bf16 scores -> exp -> branch-free pooling,
// single non-atomic store. No barriers, no atomics, no memset needed.
__global__ __launch_bounds__(256, 4) void tap_seg(
    const float* __restrict__ x,
    const int*   __restrict__ start,
    const float* __restrict__ W1,
    const float* __restrict__ b1,
    const float* __restrict__ W2,
    const float* __restrict__ b2,
    float* __restrict__ out,
    int N, int P)
{
    __shared__ float seW[4][64];          // per-wave e buffer

    const int tid  = threadIdx.x;
    const int lane = tid & 63;
    const int wave = tid >> 6;
    const int p    = blockIdx.x * 4 + wave;
    const int n16  = lane & 15;           // m (A rows) / n (B cols) index
    const int quad = lane >> 4;           // k-group

    if (p >= P) return;

    // ---- B fragments: W1[k][j], k = kt*32 + quad*8 + i, j = jt*16 + n16 ----
    // (same (quad,i)->k mapping as A frags, so any HW k-permutation cancels)
    bf16x8 bfrag[4][2];
    #pragma unroll
    for (int kt = 0; kt < 4; ++kt)
        #pragma unroll
        for (int jt = 0; jt < 2; ++jt) {
            const float* wp = W1 + (kt * 32 + quad * 8) * DH_ + jt * 16 + n16;
            union { bf16x8 v; unsigned u[4]; } bf;
            #pragma unroll
            for (int i = 0; i < 4; ++i)
                bf.u[i] = pk_bf16(wp[(2 * i) * DH_], wp[(2 * i + 1) * DH_]);
            bfrag[kt][jt] = bf.v;
        }
    float w2v[2] = { W2[n16], W2[16 + n16] };
    float b1v[2] = { b1[n16], b1[16 + n16] };
    const float b2v = b2[0];

    // ---- segment bounds (wave-uniform -> force scalar) ----
    int s0 = __builtin_amdgcn_readfirstlane(start[p]);
    int s1 = __builtin_amdgcn_readfirstlane(start[p + 1]);

    const int fo = 2 * lane;              // this lane's feature pair
    float a0 = 0.f, a1 = 0.f, ad = 0.f;

    for (int r0 = s0; r0 < s1; r0 += 64) {
        const int nrows  = min(64, s1 - r0);
        const int mtiles = (nrows + 15) >> 4;

        // ---- scores via MFMA: rows r0 .. r0+nrows ----
        f32x4 acc[4][2] = {};
        #pragma unroll
        for (int kt = 0; kt < 4; ++kt) {
            bf16x8 afrag[4];
            for (int mt = 0; mt < mtiles; ++mt) {
                int r = r0 + mt * 16 + n16; if (r > N - 1) r = N - 1;
                const float* ap = x + (size_t)r * D_ + kt * 32 + quad * 8;
                float4 v0 = *(const float4*)ap;
                float4 v1 = *(const float4*)(ap + 4);
                union { bf16x8 v; unsigned u[4]; } af;
                af.u[0] = pk_bf16(v0.x, v0.y);
                af.u[1] = pk_bf16(v0.z, v0.w);
                af.u[2] = pk_bf16(v1.x, v1.y);
                af.u[3] = pk_bf16(v1.z, v1.w);
                afrag[mt] = af.v;
            }
            for (int mt = 0; mt < mtiles; ++mt) {
                acc[mt][0] = __builtin_amdgcn_mfma_f32_16x16x32_bf16(
                    afrag[mt], bfrag[kt][0], acc[mt][0], 0, 0, 0);
                acc[mt][1] = __builtin_amdgcn_mfma_f32_16x16x32_bf16(
                    afrag[mt], bfrag[kt][1], acc[mt][1], 0, 0, 0);
            }
        }

        // ---- epilogue: e = exp(tanh(h+b1)@W2 + b2); D row = quad*4+q, col = n16 ----
        for (int mt = 0; mt < mtiles; ++mt) {
            #pragma unroll
            for (int q = 0; q < 4; ++q) {
                float s = 0.f;
                #pragma unroll
                for (int jt = 0; jt < 2; ++jt) {
                    float h = acc[mt][jt][q] + b1v[jt];
                    h = fminf(fmaxf(h, -15.f), 15.f);
                    float z = __expf(2.f * h);        // tanh via exp
                    float t = 1.f - 2.f / (z + 1.f);
                    s = fmaf(t, w2v[jt], s);
                }
                s += __shfl_xor(s, 1);
                s += __shfl_xor(s, 2);
                s += __shfl_xor(s, 4);
                s += __shfl_xor(s, 8);                // 16-lane allreduce
                if (n16 == 0)
                    seW[wave][mt * 16 + quad * 4 + q] = __expf(s + b2v);
            }
        }
        // same-wave LDS RAW: program order + lgkmcnt, no barrier needed

        // ---- branch-free pooling over exactly [r0, r0+nrows) ----
        const int rend = r0 + nrows;
        int r = r0;
        for (; r + 4 <= rend; r += 4) {
            float e0 = seW[wave][r - r0 + 0];
            float e1 = seW[wave][r - r0 + 1];
            float e2 = seW[wave][r - r0 + 2];
            float e3 = seW[wave][r - r0 + 3];
            float2 x0 = *(const float2*)&x[(size_t)(r + 0) * D_ + fo];
            float2 x1 = *(const float2*)&x[(size_t)(r + 1) * D_ + fo];
            float2 x2 = *(const float2*)&x[(size_t)(r + 2) * D_ + fo];
            float2 x3 = *(const float2*)&x[(size_t)(r + 3) * D_ + fo];
            a0 = fmaf(e0, x0.x, a0); a1 = fmaf(e0, x0.y, a1); ad += e0;
            a0 = fmaf(e1, x1.x, a0); a1 = fmaf(e1, x1.y, a1); ad += e1;
            a0 = fmaf(e2, x2.x, a0); a1 = fmaf(e2, x2.y, a1); ad += e2;
            a0 = fmaf(e3, x3.x, a0); a1 = fmaf(e3, x3.y, a1); ad += e3;
        }
        for (; r < rend; ++r) {
            float ev = seW[wave][r - r0];
            float2 xv = *(const float2*)&x[(size_t)r * D_ + fo];
            a0 = fmaf(ev, xv.x, a0); a1 = fmaf(ev, xv.y, a1); ad += ev;
        }
    }

    // ---- single owner store (covers every output element; no memset) ----
    float den = (ad == 0.f) ? 1.f : ad;   // empty-segment guard == reference
    out[(size_t)p * D_ + fo]     = a0 / den;
    out[(size_t)p * D_ + fo + 1] = a1 / den;
    if (lane == 0) out[(size_t)P * D_ + p] = (float)p;
}

extern "C" void kernel_launch(void* const* d_in, const int* in_sizes, int n_in,
                              void* d_out, int out_size, void* d_ws, size_t ws_size,
                              hipStream_t stream)
{
    const float* x   = (const float*)d_in[0];
    const int*   pid = (const int*)d_in[1];
    const float* W1  = (const float*)d_in[2];
    const float* b1  = (const float*)d_in[3];
    const float* W2  = (const float*)d_in[4];
    const float* b2  = (const float*)d_in[5];
    float* out = (float*)d_out;

    const int N = in_sizes[0] / D_;          // 1,000,000
    const int P = out_size / (D_ + 1);       // 16,384

    int* start = (int*)d_ws;                 // P+1 ints

    seg_offsets<<<(N + 255) / 256, 256, 0, stream>>>(pid, start, N, P);
    tap_seg<<<(P + 3) / 4, 256, 0, stream>>>(x, start, W1, b1, W2, b2, out, N, P);
}